// Round 2
// baseline (280.128 us; speedup 1.0000x reference)
//
#include <hip/hip_runtime.h>
#include <stdint.h>

#define HID 30
#define NCLS 10
#define SEQ 784
#define NBATCH 16384
#define TCH 112      // time steps per LDS stage
#define NSTAGE 7     // 7 * 112 = 784
#define XPAD 116     // padded LDS row stride in floats (multiple of 4)

typedef __bf16 bf16x8 __attribute__((ext_vector_type(8)));
typedef float f32x4 __attribute__((ext_vector_type(4)));
typedef uint32_t u32x4 __attribute__((ext_vector_type(4)));

static __device__ __forceinline__ bf16x8 mkfrag(uint32_t a, uint32_t b, uint32_t c, uint32_t d) {
    u32x4 t = {a, b, c, d};
    return __builtin_bit_cast(bf16x8, t);
}

// pack top-16-bits of two fp32 (bf16 truncation): low16 = even element, high16 = odd
static __device__ __forceinline__ uint32_t pk_hi(uint32_t odd_bits, uint32_t even_bits) {
    return __builtin_amdgcn_perm(odd_bits, even_bits, 0x07060302u);
}

// 3-way bf16 split of one fp32 (for the one-time A-fragment setup)
static __device__ __forceinline__ void split3(float f, uint32_t& uh, uint32_t& um, uint32_t& ul) {
    uint32_t uf = __float_as_uint(f);
    uint32_t hb = uf & 0xFFFF0000u;
    float r = f - __uint_as_float(hb);
    uint32_t ur = __float_as_uint(r);
    uint32_t mb = ur & 0xFFFF0000u;
    float lo = r - __uint_as_float(mb);
    uh = uf; um = ur; ul = __float_as_uint(lo);
}

__launch_bounds__(64, 1)
__global__ void rnn_scan_kernel(const float* __restrict__ inp,
                                const float* __restrict__ W_ih,
                                const float* __restrict__ W_hh,
                                const float* __restrict__ b_mod,
                                const float* __restrict__ W_lin,
                                const float* __restrict__ b_lin,
                                float* __restrict__ out)
{
    __shared__ __align__(16) float xs[16 * XPAD];

    const int lane = threadIdx.x;   // 0..63, one wave per block
    const int q = lane >> 4;        // k-quad: this lane holds k = 8q..8q+7 of A/B frags
    const int n = lane & 15;        // batch column within the wave's 16-batch tile
    const int b0 = blockIdx.x * 16; // this block's batch base

    // ---- A fragments: W_aug [32x32], row-permuted so D->B is lane-local ----
    // W_aug[i][j] = W_hh[i][j] (i,j<30) ; W_aug[i][30] = W_ih[i] ; else 0.
    // tile1 m-position (lane&15)=n holds W_aug row i1 = 8*(n>>2)+(n&3)
    // tile2 holds i2 = i1 + 4. Then D1 regs r = z[8q+r], D2 regs r = z[8q+4+r],
    // i.e. after modReLU each lane holds exactly h[j], j = 8q..8q+7 = its B frag.
    const int i1 = 8 * (n >> 2) + (n & 3);
    const int i2 = i1 + 4;

    uint32_t a1h[4], a1m[4], a1l[4], a2h[4], a2m[4], a2l[4];
    #pragma unroll
    for (int p = 0; p < 4; ++p) {
        uint32_t h1[2], m1[2], l1[2], h2[2], m2[2], l2[2];
        #pragma unroll
        for (int e = 0; e < 2; ++e) {
            const int j = 8 * q + 2 * p + e;
            float w1 = 0.f, w2 = 0.f;
            if (j < HID) {
                w1 = W_hh[i1 * HID + j];
                if (i2 < HID) w2 = W_hh[i2 * HID + j];
            } else if (j == HID) {
                w1 = W_ih[i1];
                if (i2 < HID) w2 = W_ih[i2];
            }
            split3(w1, h1[e], m1[e], l1[e]);
            split3(w2, h2[e], m2[e], l2[e]);
        }
        a1h[p] = pk_hi(h1[1], h1[0]); a1m[p] = pk_hi(m1[1], m1[0]); a1l[p] = pk_hi(l1[1], l1[0]);
        a2h[p] = pk_hi(h2[1], h2[0]); a2m[p] = pk_hi(m2[1], m2[0]); a2l[p] = pk_hi(l2[1], l2[0]);
    }
    const bf16x8 A1h = mkfrag(a1h[0], a1h[1], a1h[2], a1h[3]);
    const bf16x8 A1m = mkfrag(a1m[0], a1m[1], a1m[2], a1m[3]);
    const bf16x8 A1l = mkfrag(a1l[0], a1l[1], a1l[2], a1l[3]);
    const bf16x8 A2h = mkfrag(a2h[0], a2h[1], a2h[2], a2h[3]);
    const bf16x8 A2m = mkfrag(a2m[0], a2m[1], a2m[2], a2m[3]);
    const bf16x8 A2l = mkfrag(a2l[0], a2l[1], a2l[2], a2l[3]);

    // b_mod for this lane's 8 output rows (i = 8q+r and 8q+4+r); pad rows -> 0
    float bm[8];
    #pragma unroll
    for (int r = 0; r < 4; ++r) {
        const int ia = 8 * q + r;        // <= 27, always valid
        const int ib = 8 * q + 4 + r;    // up to 31
        bm[r] = b_mod[ia];
        bm[4 + r] = (ib < HID) ? b_mod[ib] : 0.f;
    }

    float h[8];
    #pragma unroll
    for (int r = 0; r < 8; ++r) h[r] = 0.f;

    const bool isq3 = (q == 3);
    const f32x4 z4 = {0.f, 0.f, 0.f, 0.f};

    for (int s = 0; s < NSTAGE; ++s) {
        // ---- stage TCH steps of inputs for 16 batch rows into LDS ----
        #pragma unroll
        for (int r = 0; r < 7; ++r) {
            const int idx = r * 64 + lane;
            const int bl = idx / 28;
            const int t4 = idx % 28;
            const float4 v = *(const float4*)(inp + (size_t)(b0 + bl) * SEQ + s * TCH + t4 * 4);
            *(float4*)(&xs[bl * XPAD + t4 * 4]) = v;
        }
        __syncthreads();

        const float* xrow = &xs[n * XPAD];
        for (int t4 = 0; t4 < 28; ++t4) {
            const float4 xv = *(const float4*)(xrow + t4 * 4); // broadcast across q
            #pragma unroll
            for (int u = 0; u < 4; ++u) {
                const float x = (u == 0) ? xv.x : (u == 1) ? xv.y : (u == 2) ? xv.z : xv.w;
                // h_aug: j=30 slot (q==3, k=6) <- x_t ; j=31 slot <- 0.
                // (for q==3 lanes, h[6]/h[7] computed to exactly 0, so selects are clean)
                float hv[8];
                #pragma unroll
                for (int k = 0; k < 6; ++k) hv[k] = h[k];
                hv[6] = isq3 ? x : h[6];
                hv[7] = isq3 ? 0.f : h[7];

                // ---- Bh: pure bit-perm of current h — ready immediately ----
                uint32_t uh[8];
                #pragma unroll
                for (int k = 0; k < 8; ++k) uh[k] = __float_as_uint(hv[k]);
                const bf16x8 Bh = mkfrag(pk_hi(uh[1], uh[0]), pk_hi(uh[3], uh[2]),
                                         pk_hi(uh[5], uh[4]), pk_hi(uh[7], uh[6]));

                // start the 6 Bh-terms while Bm/Bl split arithmetic runs
                f32x4 d1a = __builtin_amdgcn_mfma_f32_16x16x32_bf16(A1h, Bh, z4, 0, 0, 0);
                f32x4 d2a = __builtin_amdgcn_mfma_f32_16x16x32_bf16(A2h, Bh, z4, 0, 0, 0);
                f32x4 d1b = __builtin_amdgcn_mfma_f32_16x16x32_bf16(A1m, Bh, z4, 0, 0, 0);
                f32x4 d2b = __builtin_amdgcn_mfma_f32_16x16x32_bf16(A2m, Bh, z4, 0, 0, 0);
                f32x4 d1c = __builtin_amdgcn_mfma_f32_16x16x32_bf16(A1l, Bh, z4, 0, 0, 0);
                f32x4 d2c = __builtin_amdgcn_mfma_f32_16x16x32_bf16(A2l, Bh, z4, 0, 0, 0);

                // ---- Bm: first residual level ----
                float rm[8]; uint32_t um[8];
                #pragma unroll
                for (int k = 0; k < 8; ++k) {
                    rm[k] = hv[k] - __uint_as_float(uh[k] & 0xFFFF0000u);
                    um[k] = __float_as_uint(rm[k]);
                }
                const bf16x8 Bm = mkfrag(pk_hi(um[1], um[0]), pk_hi(um[3], um[2]),
                                         pk_hi(um[5], um[4]), pk_hi(um[7], um[6]));

                d1a = __builtin_amdgcn_mfma_f32_16x16x32_bf16(A1h, Bm, d1a, 0, 0, 0);
                d2a = __builtin_amdgcn_mfma_f32_16x16x32_bf16(A2h, Bm, d2a, 0, 0, 0);
                d1b = __builtin_amdgcn_mfma_f32_16x16x32_bf16(A1m, Bm, d1b, 0, 0, 0);
                d2b = __builtin_amdgcn_mfma_f32_16x16x32_bf16(A2m, Bm, d2b, 0, 0, 0);

                // ---- Bl: second residual level ----
                uint32_t ul[8];
                #pragma unroll
                for (int k = 0; k < 8; ++k) {
                    const float lo = rm[k] - __uint_as_float(um[k] & 0xFFFF0000u);
                    ul[k] = __float_as_uint(lo);
                }
                const bf16x8 Bl = mkfrag(pk_hi(ul[1], ul[0]), pk_hi(ul[3], ul[2]),
                                         pk_hi(ul[5], ul[4]), pk_hi(ul[7], ul[6]));

                d1c = __builtin_amdgcn_mfma_f32_16x16x32_bf16(A1h, Bl, d1c, 0, 0, 0);
                d2c = __builtin_amdgcn_mfma_f32_16x16x32_bf16(A2h, Bl, d2c, 0, 0, 0);

                // ---- reduce the 3 partial accumulators, modReLU ----
                const f32x4 zt1 = (d1a + d1b) + d1c;
                const f32x4 zt2 = (d2a + d2b) + d2c;
                #pragma unroll
                for (int r = 0; r < 4; ++r) {
                    const float z1 = zt1[r];
                    h[r] = __builtin_copysignf(fmaxf(__builtin_fabsf(z1) + bm[r], 0.f), z1);
                    const float z2 = zt2[r];
                    h[4 + r] = __builtin_copysignf(fmaxf(__builtin_fabsf(z2) + bm[4 + r], 0.f), z2);
                }
            }
        }
        __syncthreads();
    }

    // ---- final linear: logits = h_final @ W_lin^T + b_lin ----
    float acc[NCLS];
    #pragma unroll
    for (int c = 0; c < NCLS; ++c) {
        float p = 0.f;
        #pragma unroll
        for (int k = 0; k < 8; ++k) {
            const int j = 8 * q + k;
            if (j < HID) p += W_lin[c * HID + j] * h[k];
        }
        p += __shfl_xor(p, 16, 64);
        p += __shfl_xor(p, 32, 64);
        acc[c] = p + b_lin[c];
    }
    if (q == 0) {
        #pragma unroll
        for (int c = 0; c < NCLS; ++c)
            out[(size_t)(b0 + n) * NCLS + c] = acc[c];
    }
}

extern "C" void kernel_launch(void* const* d_in, const int* in_sizes, int n_in,
                              void* d_out, int out_size, void* d_ws, size_t ws_size,
                              hipStream_t stream) {
    const float* inp   = (const float*)d_in[0];
    const float* W_ih  = (const float*)d_in[1];
    const float* W_hh  = (const float*)d_in[2];
    const float* b_mod = (const float*)d_in[3];
    const float* W_lin = (const float*)d_in[4];
    const float* b_lin = (const float*)d_in[5];
    float* out = (float*)d_out;

    dim3 grid(NBATCH / 16);  // 1024 blocks, 16 batch rows each
    dim3 block(64);          // one wave per block
    hipLaunchKernelGGL(rnn_scan_kernel, grid, block, 0, stream,
                       inp, W_ih, W_hh, b_mod, W_lin, b_lin, out);
}

// Round 3
// 260.242 us; speedup vs baseline: 1.0764x; 1.0764x over previous
//
#include <hip/hip_runtime.h>
#include <stdint.h>
#include <math.h>

#define HID 30
#define NCLS 10
#define SEQ 784
#define NBATCH 16384
#define TCH 112      // time steps per LDS stage
#define NSTAGE 7     // 7 * 112 = 784
#define XPAD 116     // padded LDS row stride in floats

typedef _Float16 f16x8 __attribute__((ext_vector_type(8)));
typedef float f32x4 __attribute__((ext_vector_type(4)));
typedef uint32_t u32x4 __attribute__((ext_vector_type(4)));

static __device__ __forceinline__ f16x8 mkfrag16(uint32_t a, uint32_t b, uint32_t c, uint32_t d) {
    u32x4 t = {a, b, c, d};
    return __builtin_bit_cast(f16x8, t);
}

// pack two f16 (lo = element with even k, hi = odd k) into one 32-bit lane reg
static __device__ __forceinline__ uint32_t pkf16(_Float16 lo, _Float16 hi) {
    return (uint32_t)__builtin_bit_cast(unsigned short, lo)
         | ((uint32_t)__builtin_bit_cast(unsigned short, hi) << 16);
}

__launch_bounds__(64, 1)
__global__ void rnn_scan_kernel(const float* __restrict__ inp,
                                const float* __restrict__ W_ih,
                                const float* __restrict__ W_hh,
                                const float* __restrict__ b_mod,
                                const float* __restrict__ W_lin,
                                const float* __restrict__ b_lin,
                                float* __restrict__ out)
{
    __shared__ __align__(16) float xs_lds[16 * XPAD];

    const int lane = threadIdx.x;   // one wave per block
    const int q = lane >> 4;        // k-quad: lane holds k = 8q..8q+7 of A/B frags
    const int n = lane & 15;        // batch column within the wave's 16-batch tile
    const int b0 = blockIdx.x * 16;

    // ---- A fragments: W_aug [32x32], row-permuted so D->B is lane-local ----
    // W_aug[i][j] = W_hh[i][j] (i,j<30); W_aug[i][30] = W_ih[i]; else 0.
    // tile1 row i1 = 8*(n>>2)+(n&3); tile2 row i2 = i1+4. D1 reg r = z[8q+r],
    // D2 reg r = z[8q+4+r] -> after modReLU lane holds h[j], j=8q..8q+7 = its B frag.
    // 2-way f16 RNE split: A = Ah + Am with ~24-bit combined mantissa.
    const int i1 = 8 * (n >> 2) + (n & 3);
    const int i2 = i1 + 4;

    uint32_t a1h[4], a1m[4], a2h[4], a2m[4];
    #pragma unroll
    for (int p = 0; p < 4; ++p) {
        _Float16 h1[2], m1[2], h2[2], m2[2];
        #pragma unroll
        for (int e = 0; e < 2; ++e) {
            const int j = 8 * q + 2 * p + e;
            float w1 = 0.f, w2 = 0.f;
            if (j < HID) {
                w1 = W_hh[i1 * HID + j];
                if (i2 < HID) w2 = W_hh[i2 * HID + j];
            } else if (j == HID) {
                w1 = W_ih[i1];
                if (i2 < HID) w2 = W_ih[i2];
            }
            h1[e] = (_Float16)w1; m1[e] = (_Float16)(w1 - (float)h1[e]);
            h2[e] = (_Float16)w2; m2[e] = (_Float16)(w2 - (float)h2[e]);
        }
        a1h[p] = pkf16(h1[0], h1[1]); a1m[p] = pkf16(m1[0], m1[1]);
        a2h[p] = pkf16(h2[0], h2[1]); a2m[p] = pkf16(m2[0], m2[1]);
    }
    const f16x8 A1h = mkfrag16(a1h[0], a1h[1], a1h[2], a1h[3]);
    const f16x8 A1m = mkfrag16(a1m[0], a1m[1], a1m[2], a1m[3]);
    const f16x8 A2h = mkfrag16(a2h[0], a2h[1], a2h[2], a2h[3]);
    const f16x8 A2m = mkfrag16(a2m[0], a2m[1], a2m[2], a2m[3]);

    // b_mod for this lane's 8 output rows; pad rows -> 0. bS[] tracks b/S.
    float bS[8];
    #pragma unroll
    for (int r = 0; r < 4; ++r) {
        const int ia = 8 * q + r;
        const int ib = 8 * q + 4 + r;
        bS[r] = b_mod[ia];
        bS[4 + r] = (ib < HID) ? b_mod[ib] : 0.f;
    }

    // scaled state: true h = S * hh_hat; xs = 1/S (both wave-uniform powers of 2)
    float h[8];
    #pragma unroll
    for (int r = 0; r < 8; ++r) h[r] = 0.f;
    float xinv = 1.0f;   // 1/S

    const bool isq3 = (q == 3);
    const f32x4 z4 = {0.f, 0.f, 0.f, 0.f};

    for (int s = 0; s < NSTAGE; ++s) {
        // ---- stage TCH steps of inputs for 16 batch rows into LDS ----
        #pragma unroll
        for (int r = 0; r < 7; ++r) {
            const int idx = r * 64 + lane;
            const int bl = idx / 28;
            const int t4 = idx % 28;
            const float4 v = *(const float4*)(inp + (size_t)(b0 + bl) * SEQ + s * TCH + t4 * 4);
            *(float4*)(&xs_lds[bl * XPAD + t4 * 4]) = v;
        }
        __syncthreads();

        const float* xrow = &xs_lds[n * XPAD];
        for (int t8 = 0; t8 < 14; ++t8) {     // 14 * 8 = 112 steps per stage
            // ---- renormalize every 8 steps: max|h_hat| over wave -> [1,2) ----
            {
                float m01 = fmaxf(fabsf(h[0]), fabsf(h[1]));
                float m23 = fmaxf(fabsf(h[2]), fabsf(h[3]));
                float m45 = fmaxf(fabsf(h[4]), fabsf(h[5]));
                float m67 = fmaxf(fabsf(h[6]), fabsf(h[7]));
                float m = fmaxf(fmaxf(m01, m23), fmaxf(m45, m67));
                m = fmaxf(m, __shfl_xor(m, 16));
                m = fmaxf(m, __shfl_xor(m, 32));
                int ex;
                (void)frexpf(m, &ex);                  // m = f * 2^ex, f in [0.5,1)
                const float sc = ldexpf(1.0f, 1 - ex); // exact power-of-2
                #pragma unroll
                for (int r = 0; r < 8; ++r) h[r] *= sc;
                #pragma unroll
                for (int r = 0; r < 8; ++r) bS[r] *= sc;
                xinv *= sc;
            }

            #pragma unroll
            for (int tt = 0; tt < 2; ++tt) {
                const float4 xv = *(const float4*)(xrow + (t8 * 2 + tt) * 4);
                #pragma unroll
                for (int u = 0; u < 4; ++u) {
                    const float x = (u == 0) ? xv.x : (u == 1) ? xv.y : (u == 2) ? xv.z : xv.w;
                    // h_aug: j=30 slot (q==3, k=6) <- x/S ; j=31 slot stays 0 for q3
                    const float hv6 = isq3 ? (x * xinv) : h[6];

                    // ---- 2-way f16 RNE split of B ----
                    _Float16 c[8];
                    c[0] = (_Float16)h[0]; c[1] = (_Float16)h[1];
                    c[2] = (_Float16)h[2]; c[3] = (_Float16)h[3];
                    c[4] = (_Float16)h[4]; c[5] = (_Float16)h[5];
                    c[6] = (_Float16)hv6;  c[7] = (_Float16)h[7];
                    const f16x8 Bh = mkfrag16(pkf16(c[0], c[1]), pkf16(c[2], c[3]),
                                              pkf16(c[4], c[5]), pkf16(c[6], c[7]));

                    // start the Bh-dependent MFMAs while residuals are computed
                    f32x4 d1 = __builtin_amdgcn_mfma_f32_16x16x32_f16(A1h, Bh, z4, 0, 0, 0);
                    f32x4 d2 = __builtin_amdgcn_mfma_f32_16x16x32_f16(A2h, Bh, z4, 0, 0, 0);
                    d1 = __builtin_amdgcn_mfma_f32_16x16x32_f16(A1m, Bh, d1, 0, 0, 0);
                    d2 = __builtin_amdgcn_mfma_f32_16x16x32_f16(A2m, Bh, d2, 0, 0, 0);

                    _Float16 cm[8];
                    cm[0] = (_Float16)(h[0] - (float)c[0]);
                    cm[1] = (_Float16)(h[1] - (float)c[1]);
                    cm[2] = (_Float16)(h[2] - (float)c[2]);
                    cm[3] = (_Float16)(h[3] - (float)c[3]);
                    cm[4] = (_Float16)(h[4] - (float)c[4]);
                    cm[5] = (_Float16)(h[5] - (float)c[5]);
                    cm[6] = (_Float16)(hv6 - (float)c[6]);
                    cm[7] = (_Float16)(h[7] - (float)c[7]);
                    const f16x8 Bm = mkfrag16(pkf16(cm[0], cm[1]), pkf16(cm[2], cm[3]),
                                              pkf16(cm[4], cm[5]), pkf16(cm[6], cm[7]));

                    d1 = __builtin_amdgcn_mfma_f32_16x16x32_f16(A1h, Bm, d1, 0, 0, 0);
                    d2 = __builtin_amdgcn_mfma_f32_16x16x32_f16(A2h, Bm, d2, 0, 0, 0);

                    // modReLU in scaled space: h' = sign(z)*max(|z| + b/S, 0)
                    #pragma unroll
                    for (int r = 0; r < 4; ++r) {
                        const float z1 = d1[r];
                        h[r] = __builtin_copysignf(fmaxf(__builtin_fabsf(z1) + bS[r], 0.f), z1);
                        const float z2 = d2[r];
                        h[4 + r] = __builtin_copysignf(fmaxf(__builtin_fabsf(z2) + bS[4 + r], 0.f), z2);
                    }
                }
            }
        }
        __syncthreads();
    }

    // ---- final linear: logits = S * (h_hat @ W_lin^T) + b_lin ----
    const float S = 1.0f / xinv;   // exact: xinv is a power of 2
    float acc[NCLS];
    #pragma unroll
    for (int c = 0; c < NCLS; ++c) {
        float p = 0.f;
        #pragma unroll
        for (int k = 0; k < 8; ++k) {
            const int j = 8 * q + k;
            if (j < HID) p += W_lin[c * HID + j] * h[k];
        }
        p += __shfl_xor(p, 16, 64);
        p += __shfl_xor(p, 32, 64);
        acc[c] = p * S + b_lin[c];
    }
    if (q == 0) {
        #pragma unroll
        for (int c = 0; c < NCLS; ++c)
            out[(size_t)(b0 + n) * NCLS + c] = acc[c];
    }
}

extern "C" void kernel_launch(void* const* d_in, const int* in_sizes, int n_in,
                              void* d_out, int out_size, void* d_ws, size_t ws_size,
                              hipStream_t stream) {
    const float* inp   = (const float*)d_in[0];
    const float* W_ih  = (const float*)d_in[1];
    const float* W_hh  = (const float*)d_in[2];
    const float* b_mod = (const float*)d_in[3];
    const float* W_lin = (const float*)d_in[4];
    const float* b_lin = (const float*)d_in[5];
    float* out = (float*)d_out;

    dim3 grid(NBATCH / 16);  // 1024 blocks, 16 batch rows each
    dim3 block(64);          // one wave per block
    hipLaunchKernelGGL(rnn_scan_kernel, grid, block, 0, stream,
                       inp, W_ih, W_hh, b_mod, W_lin, b_lin, out);
}